// Round 25
// baseline (45.604 us; speedup 1.0000x reference)
//
#include <hip/hip_runtime.h>
#include <stdint.h>

// Single fused 3x3 neighborhood-attention kernel (R19 + shfl-free margins).
//  Pass A: block = one image row, 4 waves = 16-ch quarters, lane = quad.
//    Margins via OVERLAPPING CLAMPED LOADS instead of __shfl:
//      e0 = float2 @ max(x0-2,0); v = float4 @ x0; e1 = float2 @ min(x0+4,W-2)
//      win = {e0.y, v, e1.x}  -- clamps reproduce jnp reflect EXACTLY, no
//      fixups (x0=0: e0.y=x[1]=reflect(-1); x0=252: e1.x=x[254]=reflect(256)).
//    Removes ~190 ds_bpermute ops/wave from the load->FMA chains — the one
//    untested axis after occupancy/traffic/hold/pipe were all falsified.
//  Reduce: two rounds through [10][4][256] LDS (40,960 B); softmax; coefs LDS.
//  Pass B: same shfl-free pattern, L2/L3-hot re-read, float4 stores.
// Shapes: [b=2, c=64, h=256, w=256] fp32.

constexpr int C = 64, H = 256, W = 256, HW = H * W;
constexpr int B = 2;

__global__ __launch_bounds__(256, 2) void fused_kernel(const float* __restrict__ nbr,
                                                       const float* __restrict__ ref,
                                                       float* __restrict__ out) {
  __shared__ float buf[10][4][W];     // 40,960 B; multipurpose

  const int tid  = threadIdx.x;
  const int lane = tid & 63;          // quad index; x0 = 4*lane
  const int wv   = tid >> 6;          // channel quarter 0..3
  const int x0   = lane * 4;
  const int eL   = (x0 == 0) ? 0 : x0 - 2;        // clamped left-edge addr
  const int eR   = (x0 + 4 > W - 2) ? W - 2 : x0 + 4;  // clamped right-edge addr

  // XCD band swizzle: 512 blocks, bijective
  const int by = ((blockIdx.x & 7) << 6) | (blockIdx.x >> 3);
  const int b  = by >> 8;
  const int y  = by & 255;
  const int ym = (y == 0)     ? 1     : y - 1;   // jnp reflect
  const int yp = (y == H - 1) ? H - 2 : y + 1;

  const float* nbase = nbr + (size_t)b * C * HW;
  const float* rrow  = ref + (size_t)b * C * HW + y * W;
  float*       obase = out + (size_t)b * C * HW + y * W;
  const int oM = ym * W, oC = y * W, oP = yp * W;
  const int c0 = wv * 16;

  // ================= Pass A: accumulate (no DS ops) =================
  float dt[4][9], s2[3][6], sr[4];
#pragma unroll
  for (int e = 0; e < 4; ++e) {
    sr[e] = 0.f;
#pragma unroll
    for (int k = 0; k < 9; ++k) dt[e][k] = 0.f;
  }
#pragma unroll
  for (int r = 0; r < 3; ++r)
#pragma unroll
    for (int i = 0; i < 6; ++i) s2[r][i] = 0.f;

  const int off3[3] = {oM, oC, oP};

#pragma unroll 4
  for (int cc = 0; cc < 16; ++cc) {
    const float* cb = nbase + (size_t)(c0 + cc) * HW;
    const float4 rf = *(const float4*)(rrow + (size_t)(c0 + cc) * HW + x0);
    const float rfe[4] = {rf.x, rf.y, rf.z, rf.w};
    sr[0] = fmaf(rfe[0], rfe[0], sr[0]);
    sr[1] = fmaf(rfe[1], rfe[1], sr[1]);
    sr[2] = fmaf(rfe[2], rfe[2], sr[2]);
    sr[3] = fmaf(rfe[3], rfe[3], sr[3]);
#pragma unroll
    for (int r = 0; r < 3; ++r) {
      const float* rp = cb + off3[r];
      const float2 e0 = *(const float2*)(rp + eL);
      const float4 v  = *(const float4*)(rp + x0);
      const float2 e1 = *(const float2*)(rp + eR);
      const float win[6] = {e0.y, v.x, v.y, v.z, v.w, e1.x};
#pragma unroll
      for (int i = 0; i < 6; ++i) s2[r][i] = fmaf(win[i], win[i], s2[r][i]);
      const int kb = r * 3;
#pragma unroll
      for (int e = 0; e < 4; ++e)
#pragma unroll
        for (int cx = 0; cx < 3; ++cx)
          dt[e][kb + cx] = fmaf(rfe[e], win[e + cx], dt[e][kb + cx]);
    }
  }

  // ---- reduce round A: dt[9] + sr through buf[10] ----
#pragma unroll
  for (int k = 0; k < 9; ++k)
    *(float4*)&buf[k][wv][x0] = float4{dt[0][k], dt[1][k], dt[2][k], dt[3][k]};
  *(float4*)&buf[9][wv][x0] = float4{sr[0], sr[1], sr[2], sr[3]};
  __syncthreads();

  float td[9];
#pragma unroll
  for (int k = 0; k < 9; ++k)
    td[k] = buf[k][0][tid] + buf[k][1][tid] + buf[k][2][tid] + buf[k][3][tid];
  const float tsr = buf[9][0][tid] + buf[9][1][tid] + buf[9][2][tid] + buf[9][3][tid];
  __syncthreads();   // all round-A reads done before round-B overwrites

  // ---- reduce round B: sq[9] (from S-collapsed s2) ----
#pragma unroll
  for (int k = 0; k < 9; ++k) {
    const int r = k / 3, cx = k % 3;   // sq[e][k] = s2[r][e+cx]
    *(float4*)&buf[k][wv][x0] = float4{s2[r][cx], s2[r][cx + 1], s2[r][cx + 2], s2[r][cx + 3]};
  }
  __syncthreads();

  float tq[9];
#pragma unroll
  for (int k = 0; k < 9; ++k)
    tq[k] = buf[k][0][tid] + buf[k][1][tid] + buf[k][2][tid] + buf[k][3][tid];

  // ---- softmax (per pixel = tid) ----
  const float invr = __frsqrt_rn(fmaxf(tsr, 1e-24f));
  float d[9], invp[9];
  float mx = -INFINITY;
#pragma unroll
  for (int k = 0; k < 9; ++k) {
    invp[k] = __frsqrt_rn(fmaxf(tq[k], 1e-24f));
    d[k]    = td[k] * invr * invp[k];
    mx      = fmaxf(mx, d[k]);
  }
  float s = 0.f;
  float cfv[9];
#pragma unroll
  for (int k = 0; k < 9; ++k) {
    cfv[k] = __expf(d[k] - mx);
    s += cfv[k];
  }
  const float sinv = 1.0f / s;

  __syncthreads();   // all round-B reads done; safe to overwrite with coefs
  float* wc = &buf[0][0][0];           // coefs: wc[k*256 + px]  (9KB)
#pragma unroll
  for (int k = 0; k < 9; ++k)
    wc[k * W + tid] = cfv[k] * sinv * invp[k];   // patch l2norm folded
  __syncthreads();

  // ================= Pass B: apply (L2/L3-hot, no DS ops) =================
  float4 cf4[9];
  float2 cfe0[9], cfe1[9];             // coef windows for the edge products
#pragma unroll
  for (int k = 0; k < 9; ++k) cf4[k] = *(const float4*)&wc[k * W + x0];

#pragma unroll 2
  for (int cc = 0; cc < 16; ++cc) {
    const int c = c0 + cc;
    const float* cb = nbase + (size_t)c * HW;
    const float4 rf = *(const float4*)(rrow + (size_t)c * HW + x0);

    float agg[4] = {0.f, 0.f, 0.f, 0.f};
    float4 ac;
#pragma unroll
    for (int r = 0; r < 3; ++r) {
      const float* rp = cb + off3[r];
      const float2 e0 = *(const float2*)(rp + eL);
      const float4 v  = *(const float4*)(rp + x0);
      const float2 e1 = *(const float2*)(rp + eR);
      if (r == 1) ac = v;
      const float win[6] = {e0.y, v.x, v.y, v.z, v.w, e1.x};
#pragma unroll
      for (int cx = 0; cx < 3; ++cx) {
        const float4 cf = cf4[r * 3 + cx];
        const float cfe[4] = {cf.x, cf.y, cf.z, cf.w};
#pragma unroll
        for (int e = 0; e < 4; ++e)
          agg[e] = fmaf(cfe[e], win[e + cx], agg[e]);
      }
    }
    const float ctr[4] = {ac.x, ac.y, ac.z, ac.w};
    const float rfe[4] = {rf.x, rf.y, rf.z, rf.w};
    float oe[4];
#pragma unroll
    for (int e = 0; e < 4; ++e) {
      const float da = ctr[e] - rfe[e];
      oe[e] = agg[e] * __expf(-(da * da));   // exp(ALPHA*(nbr-ref)^2), ALPHA=-1
    }
    float4 o4;
    o4.x = oe[0]; o4.y = oe[1]; o4.z = oe[2]; o4.w = oe[3];
    *(float4*)(obase + (size_t)c * HW + x0) = o4;
  }
}

extern "C" void kernel_launch(void* const* d_in, const int* in_sizes, int n_in,
                              void* d_out, int out_size, void* d_ws, size_t ws_size,
                              hipStream_t stream) {
  const float* nbr = (const float*)d_in[0];
  const float* ref = (const float*)d_in[1];
  float*       out = (float*)d_out;
  fused_kernel<<<dim3(B * H), dim3(256), 0, stream>>>(nbr, ref, out);   // 512 row-blocks
}

// Round 26
// 31.764 us; speedup vs baseline: 1.4357x; 1.4357x over previous
//
#include <hip/hip_runtime.h>
#include <stdint.h>

// Single fused 3x3 neighborhood-attention kernel — BEST MEASURED (R19, 30.9us).
//  Pass A: block = one image row, 4 waves = 16-ch quarters, lane = quad.
//    Per channel: 3 nbr float4 + 1 ref float4 (fully coalesced), x-margins
//    via __shfl, S-collapsed sumsq accumulators.
//  Cross-wave reduce in TWO rounds through a [10][4][256] LDS buffer (40KB).
//  Softmax per pixel; coefs parked in LDS; Pass B = apply folded in
//    (L3-hot re-read, 9 coef float4 regs, coalesced stores).
//  Session record: coalescing/barriers/occupancy/reg-hold/traffic-sharing/
//  SW-pipe/LDS-staging/shfl-removal all falsified as levers; this config is
//  the pareto optimum of {VMEM instrs, DS ops, VALU, latency exposure}.
// Shapes: [b=2, c=64, h=256, w=256] fp32.

constexpr int C = 64, H = 256, W = 256, HW = H * W;
constexpr int B = 2;

__global__ __launch_bounds__(256, 2) void fused_kernel(const float* __restrict__ nbr,
                                                       const float* __restrict__ ref,
                                                       float* __restrict__ out) {
  __shared__ float buf[10][4][W];     // 40,960 B; also reused for coefs (9KB)

  const int tid  = threadIdx.x;
  const int lane = tid & 63;          // quad index; x0 = 4*lane
  const int wv   = tid >> 6;          // channel quarter 0..3
  const int x0   = lane * 4;

  // XCD band swizzle: 512 blocks, bijective
  const int by = ((blockIdx.x & 7) << 6) | (blockIdx.x >> 3);
  const int b  = by >> 8;
  const int y  = by & 255;
  const int ym = (y == 0)     ? 1     : y - 1;   // jnp reflect
  const int yp = (y == H - 1) ? H - 2 : y + 1;

  const float* nbase = nbr + (size_t)b * C * HW;
  const float* rrow  = ref + (size_t)b * C * HW + y * W;
  float*       obase = out + (size_t)b * C * HW + y * W;
  const int oM = ym * W, oC = y * W, oP = yp * W;
  const int c0 = wv * 16;

  // ================= Pass A: accumulate =================
  float dt[4][9], s2[3][6], sr[4];
#pragma unroll
  for (int e = 0; e < 4; ++e) {
    sr[e] = 0.f;
#pragma unroll
    for (int k = 0; k < 9; ++k) dt[e][k] = 0.f;
  }
#pragma unroll
  for (int r = 0; r < 3; ++r)
#pragma unroll
    for (int i = 0; i < 6; ++i) s2[r][i] = 0.f;

#pragma unroll 4
  for (int cc = 0; cc < 16; ++cc) {
    const float* cb = nbase + (size_t)(c0 + cc) * HW;
    const float4 am = *(const float4*)(cb + oM + x0);
    const float4 ac = *(const float4*)(cb + oC + x0);
    const float4 ap = *(const float4*)(cb + oP + x0);
    const float4 rf = *(const float4*)(rrow + (size_t)(c0 + cc) * HW + x0);
    const float rfe[4] = {rf.x, rf.y, rf.z, rf.w};
    sr[0] = fmaf(rfe[0], rfe[0], sr[0]);
    sr[1] = fmaf(rfe[1], rfe[1], sr[1]);
    sr[2] = fmaf(rfe[2], rfe[2], sr[2]);
    sr[3] = fmaf(rfe[3], rfe[3], sr[3]);
    const float4 rows[3] = {am, ac, ap};
#pragma unroll
    for (int r = 0; r < 3; ++r) {
      const float4 v = rows[r];
      float L = __shfl(v.w, lane - 1);
      float R = __shfl(v.x, lane + 1);
      if (lane == 0)  L = v.y;        // reflect: x=-1 -> 1
      if (lane == 63) R = v.z;        // reflect: x=256 -> 254
      const float win[6] = {L, v.x, v.y, v.z, v.w, R};
#pragma unroll
      for (int i = 0; i < 6; ++i) s2[r][i] = fmaf(win[i], win[i], s2[r][i]);
      const int kb = r * 3;
#pragma unroll
      for (int e = 0; e < 4; ++e)
#pragma unroll
        for (int cx = 0; cx < 3; ++cx)
          dt[e][kb + cx] = fmaf(rfe[e], win[e + cx], dt[e][kb + cx]);
    }
  }

  // ---- reduce round A: dt[9] + sr through buf[10] ----
#pragma unroll
  for (int k = 0; k < 9; ++k)
    *(float4*)&buf[k][wv][x0] = float4{dt[0][k], dt[1][k], dt[2][k], dt[3][k]};
  *(float4*)&buf[9][wv][x0] = float4{sr[0], sr[1], sr[2], sr[3]};
  __syncthreads();

  float td[9];
#pragma unroll
  for (int k = 0; k < 9; ++k)
    td[k] = buf[k][0][tid] + buf[k][1][tid] + buf[k][2][tid] + buf[k][3][tid];
  const float tsr = buf[9][0][tid] + buf[9][1][tid] + buf[9][2][tid] + buf[9][3][tid];
  __syncthreads();   // all round-A reads done before round-B overwrites

  // ---- reduce round B: sq[9] (from S-collapsed s2) ----
#pragma unroll
  for (int k = 0; k < 9; ++k) {
    const int r = k / 3, cx = k % 3;   // sq[e][k] = s2[r][e+cx]
    *(float4*)&buf[k][wv][x0] = float4{s2[r][cx], s2[r][cx + 1], s2[r][cx + 2], s2[r][cx + 3]};
  }
  __syncthreads();

  float tq[9];
#pragma unroll
  for (int k = 0; k < 9; ++k)
    tq[k] = buf[k][0][tid] + buf[k][1][tid] + buf[k][2][tid] + buf[k][3][tid];

  // ---- softmax (per pixel = tid) ----
  const float invr = __frsqrt_rn(fmaxf(tsr, 1e-24f));
  float d[9], invp[9];
  float mx = -INFINITY;
#pragma unroll
  for (int k = 0; k < 9; ++k) {
    invp[k] = __frsqrt_rn(fmaxf(tq[k], 1e-24f));
    d[k]    = td[k] * invr * invp[k];
    mx      = fmaxf(mx, d[k]);
  }
  float s = 0.f;
  float cfv[9];
#pragma unroll
  for (int k = 0; k < 9; ++k) {
    cfv[k] = __expf(d[k] - mx);
    s += cfv[k];
  }
  const float sinv = 1.0f / s;

  __syncthreads();   // all round-B reads done; safe to overwrite with coefs
  float* wc = &buf[0][0][0];           // coefs: wc[k*256 + px]  (9KB)
#pragma unroll
  for (int k = 0; k < 9; ++k)
    wc[k * W + tid] = cfv[k] * sinv * invp[k];   // patch l2norm folded
  __syncthreads();

  // ================= Pass B: apply (L2/L3-hot re-read) =================
  float4 cf4[9];
#pragma unroll
  for (int k = 0; k < 9; ++k) cf4[k] = *(const float4*)&wc[k * W + x0];

#pragma unroll 2
  for (int cc = 0; cc < 16; ++cc) {
    const int c = c0 + cc;
    const float* cb = nbase + (size_t)c * HW;
    const float4 am = *(const float4*)(cb + oM + x0);
    const float4 ac = *(const float4*)(cb + oC + x0);
    const float4 ap = *(const float4*)(cb + oP + x0);
    const float4 rf = *(const float4*)(rrow + (size_t)c * HW + x0);

    float agg[4] = {0.f, 0.f, 0.f, 0.f};
    const float4 rows[3] = {am, ac, ap};
#pragma unroll
    for (int r = 0; r < 3; ++r) {
      const float4 v = rows[r];
      float L = __shfl(v.w, lane - 1);
      float R = __shfl(v.x, lane + 1);
      if (lane == 0)  L = v.y;
      if (lane == 63) R = v.z;
      const float win[6] = {L, v.x, v.y, v.z, v.w, R};
#pragma unroll
      for (int cx = 0; cx < 3; ++cx) {
        const float4 cf = cf4[r * 3 + cx];
        const float cfe[4] = {cf.x, cf.y, cf.z, cf.w};
#pragma unroll
        for (int e = 0; e < 4; ++e)
          agg[e] = fmaf(cfe[e], win[e + cx], agg[e]);
      }
    }
    const float ctr[4] = {ac.x, ac.y, ac.z, ac.w};
    const float rfe[4] = {rf.x, rf.y, rf.z, rf.w};
    float oe[4];
#pragma unroll
    for (int e = 0; e < 4; ++e) {
      const float da = ctr[e] - rfe[e];
      oe[e] = agg[e] * __expf(-(da * da));   // exp(ALPHA*(nbr-ref)^2), ALPHA=-1
    }
    float4 o4;
    o4.x = oe[0]; o4.y = oe[1]; o4.z = oe[2]; o4.w = oe[3];
    *(float4*)(obase + (size_t)c * HW + x0) = o4;
  }
}

extern "C" void kernel_launch(void* const* d_in, const int* in_sizes, int n_in,
                              void* d_out, int out_size, void* d_ws, size_t ws_size,
                              hipStream_t stream) {
  const float* nbr = (const float*)d_in[0];
  const float* ref = (const float*)d_in[1];
  float*       out = (float*)d_out;
  fused_kernel<<<dim3(B * H), dim3(256), 0, stream>>>(nbr, ref, out);   // 512 row-blocks
}